// Round 10
// baseline (476.530 us; speedup 1.0000x reference)
//
#include <hip/hip_runtime.h>
#include <stdint.h>

#define NNODES 50000
#define NEDGES 800000
#define FDIM 16
#define HDIM 128
#define NPAD 50176            // 98 * 512, padded node count for the scan
#define NCH 98                // scan chunks of 512
#define NBLK64 782            // ceil(NNODES/64)

typedef __attribute__((ext_vector_type(8))) short short8;
typedef __attribute__((ext_vector_type(4))) float f32x4;

static constexpr size_t NH  = (size_t)NNODES * HDIM;   // 6.4e6 elems
static constexpr size_t NHB = NH * sizeof(float);      // 25.6 MB

// workspace layout (16B aligned)
static constexpr size_t OFF_ENC   = 0;                        // enc h1 (N x 128 u32)
static constexpr size_t OFF_PA    = NHB;                      // bf16 A0 then A2
static constexpr size_t OFF_PB    = OFF_PA + NH * 2;          // bf16 B0 then B2
static constexpr size_t OFF_QA    = OFF_PB + NH * 2;          // bf16 A1
static constexpr size_t OFF_QB    = OFF_QA + NH * 2;          // bf16 B1
static constexpr size_t OFF_CNT   = OFF_QB + NH * 2;          // NPAD x u32
static constexpr size_t OFF_CUR   = OFF_CNT + NPAD * 4;       // NPAD x u32 (end offsets)
static constexpr size_t OFF_CSUM  = OFF_CUR + NPAD * 4;       // NCH x u32 (pad 512)
static constexpr size_t OFF_COFF  = OFF_CSUM + 512;           // NCH x u32
static constexpr size_t OFF_WFOLD = OFF_COFF + 512;           // 128*4 f32
static constexpr size_t OFF_BFOLD = OFF_WFOLD + 2048;         // 4 f32
static constexpr size_t OFF_FLAG  = OFF_BFOLD + 256;          // 1 int
static constexpr size_t OFF_SEDGE = OFF_FLAG + 256;           // E x int2 (src,dst) sorted by dst
static constexpr size_t OFF_W02H  = OFF_SEDGE + (size_t)NEDGES * 8;  // 2048 units x 16B
static constexpr size_t OFF_W02L  = OFF_W02H + 32768;
static constexpr size_t OFF_W12H  = OFF_W02L + 32768;               // 2048 units
static constexpr size_t OFF_W12L  = OFF_W12H + 32768;
static constexpr size_t OFF_W11H  = OFF_W12L + 32768;               // 4096 units
static constexpr size_t OFF_W11L  = OFF_W11H + 65536;
static constexpr size_t OFF_W21H  = OFF_W11L + 65536;
static constexpr size_t OFF_W21L  = OFF_W21H + 65536;

__device__ inline unsigned enc_f32(float m) {
  unsigned u = __float_as_uint(m);
  return (u & 0x80000000u) ? ~u : (u | 0x80000000u);  // monotone encoding, enc>0 always
}

// rne fp32 -> bf16
__device__ inline ushort bf16_rne(float v) {
  const unsigned u = __float_as_uint(v);
  return (ushort)((u + 0x7fffu + ((u >> 16) & 1u)) >> 16);
}

// rne split (weights only, prep-time)
__device__ inline void bf16_split(float v, ushort& h, ushort& l) {
  unsigned u = __float_as_uint(v);
  unsigned hb = (u + 0x7fffu + ((u >> 16) & 1u)) & 0xffff0000u;
  h = (ushort)(hb >> 16);
  float r = v - __uint_as_float(hb);
  unsigned ur = __float_as_uint(r);
  l = (ushort)((ur + 0x7fffu + ((ur >> 16) & 1u)) >> 16);
}

// HW-packed rne bf16 convert: 8 floats -> 8 bf16 in 4 instructions
__device__ inline short8 cvtpk8_bf16(const float v[8]) {
  unsigned r[4];
  #pragma unroll
  for (int k = 0; k < 4; ++k)
    asm("v_cvt_pk_bf16_f32 %0, %1, %2" : "=v"(r[k]) : "v"(v[2 * k]), "v"(v[2 * k + 1]));
  return *(short8*)r;
}

__device__ inline unsigned cvtpk_bf16(float a, float b) {
  unsigned r;
  asm("v_cvt_pk_bf16_f32 %0, %1, %2" : "=v"(r) : "v"(a), "v"(b));
  return r;
}

// ---------------- init: zero outenc + cnt, edge-index dtype detect ----------
__global__ __launch_bounds__(256) void k_init(const int* __restrict__ raw,
                                              int* __restrict__ flag,
                                              unsigned* __restrict__ cnt,
                                              unsigned* __restrict__ outenc) {
  const int i = blockIdx.x * 256 + threadIdx.x;
  outenc[i] = 0u;                    // grid covers NH exactly
  if (i < NPAD) cnt[i] = 0u;
  if (i == 0) {
    int is64 = 1;
    #pragma unroll
    for (int k = 1; k < 64; k += 2)
      if (raw[k] != 0) is64 = 0;     // int64 => high dwords zero
    *flag = is64;
  }
}

__global__ __launch_bounds__(256) void k_count(const int* __restrict__ raw,
                                               const int* __restrict__ flag,
                                               unsigned* __restrict__ cnt) {
  const size_t e = (size_t)blockIdx.x * 256 + threadIdx.x;
  const int d = (*flag) ? raw[2 * ((size_t)NEDGES + e)] : raw[NEDGES + e];
  atomicAdd(&cnt[d], 1u);
}

// ---------------- prefix scan over cnt -> cursor (exclusive offsets) --------
__global__ __launch_bounds__(256) void k_scan1(const unsigned* __restrict__ cnt,
                                               unsigned* __restrict__ csum) {
  __shared__ unsigned s[256];
  const int t = threadIdx.x, b = blockIdx.x;
  s[t] = cnt[b * 512 + t] + cnt[b * 512 + 256 + t];
  __syncthreads();
  for (int off = 128; off; off >>= 1) {
    if (t < off) s[t] += s[t + off];
    __syncthreads();
  }
  if (t == 0) csum[b] = s[0];
}

__global__ void k_scan2(const unsigned* __restrict__ csum,
                        unsigned* __restrict__ coff) {
  if (threadIdx.x == 0) {
    unsigned r = 0;
    for (int i = 0; i < NCH; ++i) { coff[i] = r; r += csum[i]; }
  }
}

__global__ __launch_bounds__(256) void k_scan3(const unsigned* __restrict__ cnt,
                                               const unsigned* __restrict__ coff,
                                               unsigned* __restrict__ cursor) {
  __shared__ unsigned s[256];
  const int t = threadIdx.x, b = blockIdx.x;
  const int base = b * 512;
  const unsigned c0 = cnt[base + 2 * t], c1 = cnt[base + 2 * t + 1];
  s[t] = c0 + c1;
  __syncthreads();
  for (int off = 1; off < 256; off <<= 1) {
    unsigned v = s[t];
    if (t >= off) v += s[t - off];
    __syncthreads();
    s[t] = v;
    __syncthreads();
  }
  const unsigned o = coff[b] + s[t] - (c0 + c1);  // exclusive pair prefix
  cursor[base + 2 * t] = o;
  cursor[base + 2 * t + 1] = o + c0;
}

__global__ __launch_bounds__(256) void k_scatter(const int* __restrict__ raw,
                                                 const int* __restrict__ flag,
                                                 unsigned* __restrict__ cursor,
                                                 int2* __restrict__ sedge) {
  const size_t e = (size_t)blockIdx.x * 256 + threadIdx.x;
  int s, d;
  if (*flag) { s = raw[2 * e]; d = raw[2 * ((size_t)NEDGES + e)]; }
  else       { s = raw[e];     d = raw[NEDGES + e]; }
  const unsigned p = atomicAdd(&cursor[d], 1u);  // cursor ends at segment END
  int2 sd; sd.x = s; sd.y = d;
  sedge[p] = sd;
}

// ---------------- all weight prep in ONE kernel -----------------------------
__device__ inline void prepw_body(const float* __restrict__ W2,
                                  ushort* __restrict__ Whi,
                                  ushort* __restrict__ Wlo, int blk) {
  const int gid = blk * 256 + threadIdx.x;   // 0..2047
  const int row = gid & 15;
  const int kg  = (gid >> 4) & 3;
  const int ks  = (gid >> 6) & 3;
  const int ct  = gid >> 8;
  const int col = ct * 16 + row;
  const int k0  = ks * 32 + kg * 8;
  short8 hv, lv;
  #pragma unroll
  for (int j = 0; j < 8; ++j) {
    ushort h, l;
    bf16_split(W2[(size_t)(k0 + j) * HDIM + col], h, l);
    hv[j] = (short)h; lv[j] = (short)l;
  }
  *(short8*)(Whi + (size_t)gid * 8) = hv;
  *(short8*)(Wlo + (size_t)gid * 8) = lv;
}

__device__ inline void packab_body(const float* __restrict__ W1,
                                   ushort* __restrict__ Whi,
                                   ushort* __restrict__ Wlo, int blk) {
  const int gid = blk * 256 + threadIdx.x;   // 0..4095
  const int row = gid & 15;
  const int kg  = (gid >> 4) & 3;
  const int ks  = (gid >> 6) & 3;
  const int ct  = gid >> 8;                   // 0..15
  const int col = ct * 16 + row;
  const int k0  = ks * 32 + kg * 8;
  short8 hv, lv;
  #pragma unroll
  for (int j = 0; j < 8; ++j) {
    const int k = k0 + j;
    float v;
    if (col < HDIM) v = W1[(size_t)k * HDIM + col] - W1[(size_t)(k + HDIM) * HDIM + col];
    else            v = W1[(size_t)(k + HDIM) * HDIM + (col - HDIM)];
    ushort h, l;
    bf16_split(v, h, l);
    hv[j] = (short)h; lv[j] = (short)l;
  }
  *(short8*)(Whi + (size_t)gid * 8) = hv;
  *(short8*)(Wlo + (size_t)gid * 8) = lv;
}

__global__ __launch_bounds__(256) void k_prep_all(
    const float* __restrict__ W02, const float* __restrict__ W12,
    const float* __restrict__ W11, const float* __restrict__ W21,
    const float* __restrict__ W22, const float* __restrict__ Wf,
    const float* __restrict__ b22, const float* __restrict__ bf,
    ushort* __restrict__ W02h, ushort* __restrict__ W02l,
    ushort* __restrict__ W12h, ushort* __restrict__ W12l,
    ushort* __restrict__ W11h, ushort* __restrict__ W11l,
    ushort* __restrict__ W21h, ushort* __restrict__ W21l,
    float* __restrict__ Wfold, float* __restrict__ bfold) {
  const int b = blockIdx.x;
  if (b < 8)       prepw_body(W02, W02h, W02l, b);
  else if (b < 16) prepw_body(W12, W12h, W12l, b - 8);
  else if (b < 32) packab_body(W11, W11h, W11l, b - 16);
  else if (b < 48) packab_body(W21, W21h, W21l, b - 32);
  else {
    const int t = (b - 48) * 256 + threadIdx.x;  // 0..511
    const int f = t >> 2, o = t & 3;
    float acc = 0.f;
    for (int h = 0; h < HDIM; ++h)
      acc = fmaf(W22[f * HDIM + h], Wf[h * 4 + o], acc);
    Wfold[t] = acc;
    if (t < 4) {
      float a = bf[t];
      for (int h = 0; h < HDIM; ++h) a = fmaf(b22[h], Wf[h * 4 + t], a);
      bfold[t] = a;
    }
  }
}

// ---------------- layer-0 node projection (K=16), VALU ----------------------
__global__ __launch_bounds__(256) void k_node_ab16(const float* __restrict__ x,
                                                   const float* __restrict__ W1,
                                                   const float* __restrict__ b1,
                                                   ushort* __restrict__ Ab,
                                                   ushort* __restrict__ Bb) {
  __shared__ float s_x[16 * FDIM];
  const int tid = threadIdx.x;
  const int nb = blockIdx.x * 16;
  s_x[tid] = x[(size_t)nb * FDIM + tid];
  __syncthreads();
  const int h = tid & 127;
  const int half = tid >> 7;
  float accA[8], accB[8];
  #pragma unroll
  for (int j = 0; j < 8; ++j) { accA[j] = 0.f; accB[j] = 0.f; }
  #pragma unroll 4
  for (int f = 0; f < FDIM; ++f) {
    const float wt = W1[f * HDIM + h];
    const float wb = W1[(f + FDIM) * HDIM + h];
    const float wd = wt - wb;
    #pragma unroll
    for (int j = 0; j < 8; ++j) {
      const float xv = s_x[(half * 8 + j) * FDIM + f];
      accA[j] = fmaf(xv, wd, accA[j]);
      accB[j] = fmaf(xv, wb, accB[j]);
    }
  }
  const float bias = b1[h];
  #pragma unroll
  for (int j = 0; j < 8; ++j) {
    const size_t idx = (size_t)(nb + half * 8 + j) * HDIM + h;
    Ab[idx] = bf16_rne(accA[j] + bias);
    Bb[idx] = bf16_rne(accB[j]);
  }
}

// ---------------- layer-1 node A|B projection: 2-term MFMA ------------------
// input: encoded h1 (decode inline, cvt to single bf16); weights split hi/lo.
__global__ __launch_bounds__(256) void k_node_ab_mfma(
    const unsigned* __restrict__ X, const ushort* __restrict__ Whi,
    const ushort* __restrict__ Wlo, const float* __restrict__ b1,
    ushort* __restrict__ Ab, ushort* __restrict__ Bb) {
  __shared__ __align__(16) ushort s_t[64 * 128];
  const int tid = threadIdx.x;
  const int nb = blockIdx.x * 64;

  #pragma unroll
  for (int it = 0; it < 4; ++it) {
    const int idx = tid + it * 256;
    const int row = idx >> 4;
    const int kg8 = idx & 15;
    const int n = nb + row;
    float v[8];
    if (n < NNODES) {
      const unsigned* p = X + (size_t)n * HDIM + kg8 * 8;
      const uint4 u0 = *(const uint4*)p;
      const uint4 u1 = *(const uint4*)(p + 4);
      const unsigned uu[8] = {u0.x, u0.y, u0.z, u0.w, u1.x, u1.y, u1.z, u1.w};
      #pragma unroll
      for (int j = 0; j < 8; ++j)
        v[j] = (uu[j] & 0x80000000u) ? __uint_as_float(uu[j] ^ 0x80000000u) : 0.f;
    } else {
      #pragma unroll
      for (int j = 0; j < 8; ++j) v[j] = 0.f;
    }
    const short8 hv = cvtpk8_bf16(v);
    const int unit = row * 16 + (kg8 ^ (row & 15));
    *(short8*)(s_t + unit * 8) = hv;
  }
  __syncthreads();

  const int l15 = tid & 15;
  const int l4  = (tid >> 4) & 3;
  const int w   = tid >> 6;

  f32x4 acc[4][4];
  #pragma unroll
  for (int rt = 0; rt < 4; ++rt)
    #pragma unroll
    for (int c = 0; c < 4; ++c)
      #pragma unroll
      for (int r = 0; r < 4; ++r) acc[rt][c][r] = 0.f;

  #pragma unroll
  for (int ks = 0; ks < 4; ++ks) {
    short8 wh[4], wl[4];
    #pragma unroll
    for (int ctl = 0; ctl < 4; ++ctl) {
      const int ct_g = w * 4 + ctl;
      const size_t u = ((size_t)(((ct_g * 4 + ks) * 4 + l4) * 16 + l15)) * 8;
      wh[ctl] = *(const short8*)(Whi + u);
      wl[ctl] = *(const short8*)(Wlo + u);
    }
    #pragma unroll
    for (int rt = 0; rt < 4; ++rt) {
      const int unit = (rt * 16 + l15) * 16 + ((ks * 4 + l4) ^ l15);
      const short8 ah = *(const short8*)(s_t + unit * 8);
      #pragma unroll
      for (int ctl = 0; ctl < 4; ++ctl) {
        acc[rt][ctl] = __builtin_amdgcn_mfma_f32_16x16x32_bf16(ah, wl[ctl], acc[rt][ctl], 0, 0, 0);
        acc[rt][ctl] = __builtin_amdgcn_mfma_f32_16x16x32_bf16(ah, wh[ctl], acc[rt][ctl], 0, 0, 0);
      }
    }
  }

  #pragma unroll
  for (int ctl = 0; ctl < 4; ++ctl) {
    const int col_g = w * 64 + ctl * 16 + l15;
    if (col_g < HDIM) {
      const float bias = b1[col_g];
      #pragma unroll
      for (int rt = 0; rt < 4; ++rt)
        #pragma unroll
        for (int r = 0; r < 4; ++r) {
          const int n = nb + rt * 16 + l4 * 4 + r;
          if (n < NNODES) Ab[(size_t)n * HDIM + col_g] = bf16_rne(acc[rt][ctl][r] + bias);
        }
    } else {
      const int cb = col_g - HDIM;
      #pragma unroll
      for (int rt = 0; rt < 4; ++rt)
        #pragma unroll
        for (int r = 0; r < 4; ++r) {
          const int n = nb + rt * 16 + l4 * 4 + r;
          if (n < NNODES) Bb[(size_t)n * HDIM + cb] = bf16_rne(acc[rt][ctl][r]);
        }
    }
  }
}

// ---------------- layer-2 mega: CSR mean-gather + GEMM1 + GEMM2 -------------
// gather: mean_e relu(A1[n]+B1[src]) -> bf16 staging LDS (no S round-trip)
// GEMM1: h2 = relu(mean @ W12 + b12)*alive  (2-term, stays in LDS)
// GEMM2: A2|B2 = h2 @ Wcat21 (+b21 on A)    (2-term, bf16 outputs)
__global__ __launch_bounds__(256) void k_l2_mega(
    const ushort* __restrict__ A1, const ushort* __restrict__ B1,
    const int2* __restrict__ sedge, const unsigned* __restrict__ endv,
    const unsigned* __restrict__ cnt,
    const ushort* __restrict__ W12h, const ushort* __restrict__ W12l,
    const float* __restrict__ b12,
    const ushort* __restrict__ W21h, const ushort* __restrict__ W21l,
    const float* __restrict__ b21,
    ushort* __restrict__ A2, ushort* __restrict__ B2) {
  __shared__ __align__(16) ushort s_t[64 * 128];
  __shared__ float s_m[64 * 132];
  __shared__ float s_scale[64];
  __shared__ float s_alive[64];
  const int tid = threadIdx.x;
  const int nb = blockIdx.x * 64;
  if (tid < 64) {
    const int n = nb + tid;
    const unsigned c = (n < NNODES) ? cnt[n] : 0u;
    s_scale[tid] = c ? 1.f / (float)c : 0.f;
    s_alive[tid] = c ? 1.f : 0.f;
  }
  __syncthreads();

  const int w    = tid >> 6;
  const int lane = tid & 63;

  // ---- gather phase: wave w handles rows w*16 .. w*16+15 ----
  for (int ln = 0; ln < 16; ++ln) {
    const int row = w * 16 + ln;
    const int n = nb + row;
    float sx = 0.f, sy = 0.f;
    float ax = 0.f, ay = 0.f;
    unsigned deg = 0, end = 0;
    if (n < NNODES) {
      deg = cnt[n];
      end = endv[n];
      const unsigned a_dw = *(const unsigned*)(A1 + (size_t)n * HDIM + lane * 2);
      ax = __uint_as_float(a_dw << 16);
      ay = __uint_as_float(a_dw & 0xffff0000u);
    }
    const unsigned start = end - deg;
    for (unsigned cb = start; cb < end; cb += 64) {
      const int m = (int)((end - cb < 64u) ? (end - cb) : 64u);
      int myidx = 0;
      if (lane < m) myidx = sedge[cb + lane].x;
      int k = 0;
      for (; k + 8 <= m; k += 8) {
        unsigned bv[8];
        #pragma unroll
        for (int j = 0; j < 8; ++j) {
          const int id = __shfl(myidx, k + j);
          bv[j] = *(const unsigned*)(B1 + (size_t)id * HDIM + lane * 2);
        }
        #pragma unroll
        for (int j = 0; j < 8; ++j) {
          sx += fmaxf(ax + __uint_as_float(bv[j] << 16), 0.f);
          sy += fmaxf(ay + __uint_as_float(bv[j] & 0xffff0000u), 0.f);
        }
      }
      for (; k < m; ++k) {
        const int id = __shfl(myidx, k);
        const unsigned bv = *(const unsigned*)(B1 + (size_t)id * HDIM + lane * 2);
        sx += fmaxf(ax + __uint_as_float(bv << 16), 0.f);
        sy += fmaxf(ay + __uint_as_float(bv & 0xffff0000u), 0.f);
      }
    }
    const float sc = s_scale[row];
    const unsigned pk = cvtpk_bf16(sx * sc, sy * sc);
    // staging unit layout: unit = row*16 + (kg8 ^ (row&15)), kg8 = lane>>2
    const int unit = row * 16 + ((lane >> 2) ^ (row & 15));
    *(unsigned*)((char*)s_t + unit * 16 + (lane & 3) * 4) = pk;
  }
  __syncthreads();

  const int l15 = tid & 15;
  const int l4  = (tid >> 4) & 3;

  // ---- GEMM1: 128 cols (2 ctl/wave), 2-term ----
  {
    f32x4 acc[4][2];
    #pragma unroll
    for (int rt = 0; rt < 4; ++rt)
      #pragma unroll
      for (int c = 0; c < 2; ++c)
        #pragma unroll
        for (int r = 0; r < 4; ++r) acc[rt][c][r] = 0.f;

    #pragma unroll
    for (int ks = 0; ks < 4; ++ks) {
      short8 wh[2], wl[2];
      #pragma unroll
      for (int ctl = 0; ctl < 2; ++ctl) {
        const int ct_g = w * 2 + ctl;
        const size_t u = ((size_t)(((ct_g * 4 + ks) * 4 + l4) * 16 + l15)) * 8;
        wh[ctl] = *(const short8*)(W12h + u);
        wl[ctl] = *(const short8*)(W12l + u);
      }
      #pragma unroll
      for (int rt = 0; rt < 4; ++rt) {
        const int unit = (rt * 16 + l15) * 16 + ((ks * 4 + l4) ^ l15);
        const short8 ah = *(const short8*)(s_t + unit * 8);
        #pragma unroll
        for (int ctl = 0; ctl < 2; ++ctl) {
          acc[rt][ctl] = __builtin_amdgcn_mfma_f32_16x16x32_bf16(ah, wl[ctl], acc[rt][ctl], 0, 0, 0);
          acc[rt][ctl] = __builtin_amdgcn_mfma_f32_16x16x32_bf16(ah, wh[ctl], acc[rt][ctl], 0, 0, 0);
        }
      }
    }

    const float bb0 = b12[w * 32 + l15];
    const float bb1 = b12[w * 32 + 16 + l15];
    #pragma unroll
    for (int rt = 0; rt < 4; ++rt)
      #pragma unroll
      for (int ctl = 0; ctl < 2; ++ctl)
        #pragma unroll
        for (int r = 0; r < 4; ++r) {
          const int row = rt * 16 + l4 * 4 + r;
          s_m[row * 132 + w * 32 + ctl * 16 + l15] =
              fmaxf(acc[rt][ctl][r] + (ctl ? bb1 : bb0), 0.f) * s_alive[row];
        }
  }
  __syncthreads();

  // restage h2 -> bf16 staging LDS
  #pragma unroll
  for (int it = 0; it < 4; ++it) {
    const int idx = tid + it * 256;
    const int row = idx >> 4;
    const int kg8 = idx & 15;
    const float* p = s_m + row * 132 + kg8 * 8;
    float v[8];
    const float4 a0 = *(const float4*)p;
    const float4 a1 = *(const float4*)(p + 4);
    v[0] = a0.x; v[1] = a0.y; v[2] = a0.z; v[3] = a0.w;
    v[4] = a1.x; v[5] = a1.y; v[6] = a1.z; v[7] = a1.w;
    const short8 hv = cvtpk8_bf16(v);
    const int unit = row * 16 + (kg8 ^ (row & 15));
    *(short8*)(s_t + unit * 8) = hv;
  }
  __syncthreads();

  // ---- GEMM2: 256 cols (4 ctl/wave), 2-term ----
  f32x4 acc2[4][4];
  #pragma unroll
  for (int rt = 0; rt < 4; ++rt)
    #pragma unroll
    for (int c = 0; c < 4; ++c)
      #pragma unroll
      for (int r = 0; r < 4; ++r) acc2[rt][c][r] = 0.f;

  #pragma unroll
  for (int ks = 0; ks < 4; ++ks) {
    short8 wh[4], wl[4];
    #pragma unroll
    for (int ctl = 0; ctl < 4; ++ctl) {
      const int ct_g = w * 4 + ctl;
      const size_t u = ((size_t)(((ct_g * 4 + ks) * 4 + l4) * 16 + l15)) * 8;
      wh[ctl] = *(const short8*)(W21h + u);
      wl[ctl] = *(const short8*)(W21l + u);
    }
    #pragma unroll
    for (int rt = 0; rt < 4; ++rt) {
      const int unit = (rt * 16 + l15) * 16 + ((ks * 4 + l4) ^ l15);
      const short8 ah = *(const short8*)(s_t + unit * 8);
      #pragma unroll
      for (int ctl = 0; ctl < 4; ++ctl) {
        acc2[rt][ctl] = __builtin_amdgcn_mfma_f32_16x16x32_bf16(ah, wl[ctl], acc2[rt][ctl], 0, 0, 0);
        acc2[rt][ctl] = __builtin_amdgcn_mfma_f32_16x16x32_bf16(ah, wh[ctl], acc2[rt][ctl], 0, 0, 0);
      }
    }
  }

  #pragma unroll
  for (int ctl = 0; ctl < 4; ++ctl) {
    const int col_g = w * 64 + ctl * 16 + l15;
    if (col_g < HDIM) {
      const float bias = b21[col_g];
      #pragma unroll
      for (int rt = 0; rt < 4; ++rt)
        #pragma unroll
        for (int r = 0; r < 4; ++r) {
          const int n = nb + rt * 16 + l4 * 4 + r;
          if (n < NNODES) A2[(size_t)n * HDIM + col_g] = bf16_rne(acc2[rt][ctl][r] + bias);
        }
    } else {
      const int cb = col_g - HDIM;
      #pragma unroll
      for (int rt = 0; rt < 4; ++rt)
        #pragma unroll
        for (int r = 0; r < 4; ++r) {
          const int n = nb + rt * 16 + l4 * 4 + r;
          if (n < NNODES) B2[(size_t)n * HDIM + cb] = bf16_rne(acc2[rt][ctl][r]);
        }
    }
  }
}

// ---------------- layer 0: single-bf16 MFMA edge GEMM + register seg-max ----
__global__ __launch_bounds__(256) void k_edge_l0_mfma(
    const ushort* __restrict__ A0b, const ushort* __restrict__ B0b,
    const int2* __restrict__ sedge,
    const ushort* __restrict__ Whi,
    const float* __restrict__ b2, unsigned* __restrict__ outenc) {
  __shared__ __align__(16) char s_un[4 * 64 * 17 * 4];  // m slabs 17408B | t 16384B
  __shared__ int s_dstA[64];
  __shared__ int s_srcA[64];
  ushort* s_t = (ushort*)s_un;
  float*  s_m = (float*)s_un;

  const int tid = threadIdx.x;
  const int eb = blockIdx.x * 64;
  if (tid < 64) {
    const int2 sd = sedge[eb + tid];
    s_srcA[tid] = sd.x;
    s_dstA[tid] = sd.y;
  }
  __syncthreads();

  #pragma unroll
  for (int it = 0; it < 4; ++it) {
    const int idx = tid + it * 256;
    const int e = idx >> 4;
    const int kg8 = idx & 15;
    const int k0 = kg8 * 8;
    const short8 a8 = *(const short8*)(A0b + (size_t)s_dstA[e] * HDIM + k0);
    const short8 b8 = *(const short8*)(B0b + (size_t)s_srcA[e] * HDIM + k0);
    float v[8];
    #pragma unroll
    for (int j = 0; j < 8; ++j) {
      const float av = __uint_as_float(((unsigned)(ushort)a8[j]) << 16);
      const float bv = __uint_as_float(((unsigned)(ushort)b8[j]) << 16);
      v[j] = fmaxf(av + bv, 0.f);
    }
    const short8 hv = cvtpk8_bf16(v);
    const int unit = e * 16 + (kg8 ^ (e & 15));
    *(short8*)(s_t + unit * 8) = hv;
  }
  __syncthreads();

  const int l15 = tid & 15;
  const int l4  = (tid >> 4) & 3;
  const int w   = tid >> 6;

  f32x4 acc[4][2];
  #pragma unroll
  for (int rt = 0; rt < 4; ++rt)
    #pragma unroll
    for (int c = 0; c < 2; ++c)
      #pragma unroll
      for (int r = 0; r < 4; ++r) acc[rt][c][r] = 0.f;

  #pragma unroll
  for (int ks = 0; ks < 4; ++ks) {
    short8 wh[2];
    #pragma unroll
    for (int ctl = 0; ctl < 2; ++ctl) {
      const int ct_g = w * 2 + ctl;
      const size_t u = ((size_t)(((ct_g * 4 + ks) * 4 + l4) * 16 + l15)) * 8;
      wh[ctl] = *(const short8*)(Whi + u);
    }
    #pragma unroll
    for (int rt = 0; rt < 4; ++rt) {
      const int e = rt * 16 + l15;
      const int unit = e * 16 + ((ks * 4 + l4) ^ l15);
      const short8 ah = *(const short8*)(s_t + unit * 8);
      #pragma unroll
      for (int ctl = 0; ctl < 2; ++ctl)
        acc[rt][ctl] = __builtin_amdgcn_mfma_f32_16x16x32_bf16(ah, wh[ctl], acc[rt][ctl], 0, 0, 0);
    }
  }
  __syncthreads();

  // 2-pass epilogue with register-prefetched segmented max
  float* smw = s_m + w * (64 * 17);
  const int le = tid & 63;
  const int colw = le & 15;
  const int g = le >> 4;
  const int e0 = g * 16;
  int dd[16];
  #pragma unroll
  for (int e = 0; e < 16; ++e) dd[e] = s_dstA[e0 + e];
  #pragma unroll
  for (int ctl = 0; ctl < 2; ++ctl) {
    const float bb = b2[w * 32 + ctl * 16 + l15];
    #pragma unroll
    for (int rt = 0; rt < 4; ++rt)
      #pragma unroll
      for (int r = 0; r < 4; ++r)
        smw[(rt * 16 + l4 * 4 + r) * 17 + l15] = acc[rt][ctl][r] + bb;
    float vv[16];
    #pragma unroll
    for (int e = 0; e < 16; ++e) vv[e] = smw[(e0 + e) * 17 + colw];
    unsigned* const ocol = outenc + w * 32 + ctl * 16 + colw;
    int curd = dd[0];
    float run = vv[0];
    #pragma unroll
    for (int e = 1; e < 16; ++e) {
      const bool same = (dd[e] == curd);
      if (!same) atomicMax(ocol + (size_t)curd * HDIM, enc_f32(run));
      run = same ? fmaxf(run, vv[e]) : vv[e];
      curd = dd[e];
    }
    atomicMax(ocol + (size_t)curd * HDIM, enc_f32(run));
  }
}

// ---------------- layer-2 mean fused with final fc (A2/B2 bf16) -------------
__global__ __launch_bounds__(256) void k_seg_final(const ushort* __restrict__ A,
                                                   const ushort* __restrict__ B,
                                                   const int2* __restrict__ sedge,
                                                   const unsigned* __restrict__ endv,
                                                   const unsigned* __restrict__ cnt,
                                                   const float* __restrict__ Wfold,
                                                   const float* __restrict__ bfold,
                                                   const float* __restrict__ bf,
                                                   float* __restrict__ out) {
  const int tid = threadIdx.x;
  const int n = blockIdx.x * 4 + (tid >> 6);
  const int lane = tid & 63;
  const unsigned deg = cnt[n];
  if (deg == 0) {
    if (lane == 0) {
      float4 o; o.x = bf[0]; o.y = bf[1]; o.z = bf[2]; o.w = bf[3];
      ((float4*)out)[n] = o;
    }
    return;
  }
  const unsigned end = endv[n];
  const unsigned start = end - deg;
  const unsigned a_dw = *(const unsigned*)(A + (size_t)n * HDIM + lane * 2);
  const float ax = __uint_as_float(a_dw << 16);
  const float ay = __uint_as_float(a_dw & 0xffff0000u);
  float sx = 0.f, sy = 0.f;
  for (unsigned cb = start; cb < end; cb += 64) {
    const int m = (int)((end - cb < 64u) ? (end - cb) : 64u);
    int myidx = 0;
    if (lane < m) myidx = sedge[cb + lane].x;
    int k = 0;
    for (; k + 8 <= m; k += 8) {
      unsigned bv[8];
      #pragma unroll
      for (int j = 0; j < 8; ++j) {
        const int id = __shfl(myidx, k + j);
        bv[j] = *(const unsigned*)(B + (size_t)id * HDIM + lane * 2);
      }
      #pragma unroll
      for (int j = 0; j < 8; ++j) {
        sx += fmaxf(ax + __uint_as_float(bv[j] << 16), 0.f);
        sy += fmaxf(ay + __uint_as_float(bv[j] & 0xffff0000u), 0.f);
      }
    }
    for (; k < m; ++k) {
      const int id = __shfl(myidx, k);
      const unsigned bv = *(const unsigned*)(B + (size_t)id * HDIM + lane * 2);
      sx += fmaxf(ax + __uint_as_float(bv << 16), 0.f);
      sy += fmaxf(ay + __uint_as_float(bv & 0xffff0000u), 0.f);
    }
  }
  const float inv = 1.f / (float)deg;
  const float vx = sx * inv, vy = sy * inv;
  const float4 w0 = ((const float4*)Wfold)[lane * 2];
  const float4 w1 = ((const float4*)Wfold)[lane * 2 + 1];
  float p0 = fmaf(vx, w0.x, vy * w1.x);
  float p1 = fmaf(vx, w0.y, vy * w1.y);
  float p2 = fmaf(vx, w0.z, vy * w1.z);
  float p3 = fmaf(vx, w0.w, vy * w1.w);
  #pragma unroll
  for (int off = 32; off; off >>= 1) {
    p0 += __shfl_xor(p0, off);
    p1 += __shfl_xor(p1, off);
    p2 += __shfl_xor(p2, off);
    p3 += __shfl_xor(p3, off);
  }
  if (lane == 0) {
    float4 o;
    o.x = p0 + bfold[0]; o.y = p1 + bfold[1];
    o.z = p2 + bfold[2]; o.w = p3 + bfold[3];
    ((float4*)out)[n] = o;
  }
}

// ----------------------------------------------------------------------------
extern "C" void kernel_launch(void* const* d_in, const int* in_sizes, int n_in,
                              void* d_out, int out_size, void* d_ws, size_t ws_size,
                              hipStream_t stream) {
  const float* x   = (const float*)d_in[0];
  // d_in[1] = edge_attr: unused in math
  const int*   eidx = (const int*)d_in[2];
  const float* W01 = (const float*)d_in[3];
  const float* b01 = (const float*)d_in[4];
  const float* W02 = (const float*)d_in[5];
  const float* b02 = (const float*)d_in[6];
  const float* W11 = (const float*)d_in[7];
  const float* b11 = (const float*)d_in[8];
  const float* W12 = (const float*)d_in[9];
  const float* b12 = (const float*)d_in[10];
  const float* W21 = (const float*)d_in[11];
  const float* b21 = (const float*)d_in[12];
  const float* W22 = (const float*)d_in[13];
  const float* b22 = (const float*)d_in[14];
  const float* Wf  = (const float*)d_in[15];
  const float* bf  = (const float*)d_in[16];
  float* out = (float*)d_out;
  char* ws = (char*)d_ws;

  unsigned* enc = (unsigned*)(ws + OFF_ENC);
  ushort* PA = (ushort*)(ws + OFF_PA);   // A0 then A2
  ushort* PB = (ushort*)(ws + OFF_PB);   // B0 then B2
  ushort* QA = (ushort*)(ws + OFF_QA);   // A1
  ushort* QB = (ushort*)(ws + OFF_QB);   // B1
  unsigned* cnt    = (unsigned*)(ws + OFF_CNT);
  unsigned* cursor = (unsigned*)(ws + OFF_CUR);
  unsigned* csum   = (unsigned*)(ws + OFF_CSUM);
  unsigned* coff   = (unsigned*)(ws + OFF_COFF);
  float* Wfold = (float*)(ws + OFF_WFOLD);
  float* bfold = (float*)(ws + OFF_BFOLD);
  int* flag  = (int*)(ws + OFF_FLAG);
  int2* sedge = (int2*)(ws + OFF_SEDGE);
  ushort* W02h = (ushort*)(ws + OFF_W02H);
  ushort* W02l = (ushort*)(ws + OFF_W02L);
  ushort* W12h = (ushort*)(ws + OFF_W12H);
  ushort* W12l = (ushort*)(ws + OFF_W12L);
  ushort* W11h = (ushort*)(ws + OFF_W11H);
  ushort* W11l = (ushort*)(ws + OFF_W11L);
  ushort* W21h = (ushort*)(ws + OFF_W21H);
  ushort* W21l = (ushort*)(ws + OFF_W21L);

  // ---- init (zero enc+cnt, detect dtype) + counting sort + weight prep ----
  k_init<<<(int)(NH / 256), 256, 0, stream>>>(eidx, flag, cnt, enc);
  k_count<<<NEDGES / 256, 256, 0, stream>>>(eidx, flag, cnt);
  k_scan1<<<NCH, 256, 0, stream>>>(cnt, csum);
  k_scan2<<<1, 64, 0, stream>>>(csum, coff);
  k_scan3<<<NCH, 256, 0, stream>>>(cnt, coff, cursor);
  k_scatter<<<NEDGES / 256, 256, 0, stream>>>(eidx, flag, cursor, sedge);
  // after scatter: cursor[n] == segment end offset of node n
  k_prep_all<<<50, 256, 0, stream>>>(W02, W12, W11, W21, W22, Wf, b22, bf,
                                     W02h, W02l, W12h, W12l, W11h, W11l,
                                     W21h, W21l, Wfold, bfold);

  // ---- layer 0 (max aggr) ----
  k_node_ab16<<<NNODES / 16, 256, 0, stream>>>(x, W01, b01, PA, PB);
  k_edge_l0_mfma<<<NEDGES / 64, 256, 0, stream>>>(PA, PB, sedge, W02h, b02, enc);

  // ---- layer 1 projections (2-term MFMA, bf16 outputs) ----
  k_node_ab_mfma<<<NBLK64, 256, 0, stream>>>(enc, W11h, W11l, b11, QA, QB);

  // ---- layer 2 mega: mean-gather + GEMM1 + GEMM2 ----
  k_l2_mega<<<NBLK64, 256, 0, stream>>>(QA, QB, sedge, cursor, cnt,
                                        W12h, W12l, b12, W21h, W21l, b21,
                                        PA, PB);

  // ---- final: mean + folded fc ----
  k_seg_final<<<NNODES / 4, 256, 0, stream>>>(PA, PB, sedge, cursor, cnt,
                                              Wfold, bfold, bf, out);

  (void)in_sizes; (void)n_in; (void)out_size; (void)ws_size;
}

// Round 12
// 419.868 us; speedup vs baseline: 1.1350x; 1.1350x over previous
//
#include <hip/hip_runtime.h>
#include <stdint.h>

#define NNODES 50000
#define NEDGES 800000
#define FDIM 16
#define HDIM 128
#define NPAD 50176            // 98 * 512, padded node count for the scan
#define NCH 98                // scan chunks of 512
#define NBLK64 782            // ceil(NNODES/64)

typedef __attribute__((ext_vector_type(8))) short short8;
typedef __attribute__((ext_vector_type(4))) float f32x4;

static constexpr size_t NH  = (size_t)NNODES * HDIM;   // 6.4e6 elems
static constexpr size_t NHB = NH * sizeof(float);      // 25.6 MB

// workspace layout (16B aligned)
static constexpr size_t OFF_ENC   = 0;                        // enc h1 (N x 128 u32); later bf16 mean Sb
static constexpr size_t OFF_PA    = NHB;                      // bf16 A0 then A2
static constexpr size_t OFF_PB    = OFF_PA + NH * 2;          // bf16 B0 then B2
static constexpr size_t OFF_QA    = OFF_PB + NH * 2;          // bf16 A1
static constexpr size_t OFF_QB    = OFF_QA + NH * 2;          // bf16 B1
static constexpr size_t OFF_CNT   = OFF_QB + NH * 2;          // NPAD x u32
static constexpr size_t OFF_CUR   = OFF_CNT + NPAD * 4;       // NPAD x u32 (end offsets)
static constexpr size_t OFF_CSUM  = OFF_CUR + NPAD * 4;       // NCH x u32 (pad 512)
static constexpr size_t OFF_COFF  = OFF_CSUM + 512;           // NCH x u32
static constexpr size_t OFF_WFOLD = OFF_COFF + 512;           // 128*4 f32
static constexpr size_t OFF_BFOLD = OFF_WFOLD + 2048;         // 4 f32
static constexpr size_t OFF_FLAG  = OFF_BFOLD + 256;          // 1 int
static constexpr size_t OFF_SEDGE = OFF_FLAG + 256;           // E x int2 (src,dst) sorted by dst
static constexpr size_t OFF_W02H  = OFF_SEDGE + (size_t)NEDGES * 8;  // 2048 units x 16B
static constexpr size_t OFF_W02L  = OFF_W02H + 32768;
static constexpr size_t OFF_W12H  = OFF_W02L + 32768;               // 2048 units
static constexpr size_t OFF_W12L  = OFF_W12H + 32768;
static constexpr size_t OFF_W11H  = OFF_W12L + 32768;               // 4096 units
static constexpr size_t OFF_W11L  = OFF_W11H + 65536;
static constexpr size_t OFF_W21H  = OFF_W11L + 65536;
static constexpr size_t OFF_W21L  = OFF_W21H + 65536;

__device__ inline unsigned enc_f32(float m) {
  unsigned u = __float_as_uint(m);
  return (u & 0x80000000u) ? ~u : (u | 0x80000000u);  // monotone encoding, enc>0 always
}

// rne fp32 -> bf16
__device__ inline ushort bf16_rne(float v) {
  const unsigned u = __float_as_uint(v);
  return (ushort)((u + 0x7fffu + ((u >> 16) & 1u)) >> 16);
}

// rne split (weights only, prep-time)
__device__ inline void bf16_split(float v, ushort& h, ushort& l) {
  unsigned u = __float_as_uint(v);
  unsigned hb = (u + 0x7fffu + ((u >> 16) & 1u)) & 0xffff0000u;
  h = (ushort)(hb >> 16);
  float r = v - __uint_as_float(hb);
  unsigned ur = __float_as_uint(r);
  l = (ushort)((ur + 0x7fffu + ((ur >> 16) & 1u)) >> 16);
}

// HW-packed rne bf16 convert: 8 floats -> 8 bf16 in 4 instructions
__device__ inline short8 cvtpk8_bf16(const float v[8]) {
  unsigned r[4];
  #pragma unroll
  for (int k = 0; k < 4; ++k)
    asm("v_cvt_pk_bf16_f32 %0, %1, %2" : "=v"(r[k]) : "v"(v[2 * k]), "v"(v[2 * k + 1]));
  return *(short8*)r;
}

__device__ inline unsigned cvtpk_bf16(float a, float b) {
  unsigned r;
  asm("v_cvt_pk_bf16_f32 %0, %1, %2" : "=v"(r) : "v"(a), "v"(b));
  return r;
}

// ---------------- init: zero outenc + cnt, edge-index dtype detect ----------
__global__ __launch_bounds__(256) void k_init(const int* __restrict__ raw,
                                              int* __restrict__ flag,
                                              unsigned* __restrict__ cnt,
                                              unsigned* __restrict__ outenc) {
  const int i = blockIdx.x * 256 + threadIdx.x;
  outenc[i] = 0u;                    // grid covers NH exactly
  if (i < NPAD) cnt[i] = 0u;
  if (i == 0) {
    int is64 = 1;
    #pragma unroll
    for (int k = 1; k < 64; k += 2)
      if (raw[k] != 0) is64 = 0;     // int64 => high dwords zero
    *flag = is64;
  }
}

__global__ __launch_bounds__(256) void k_count(const int* __restrict__ raw,
                                               const int* __restrict__ flag,
                                               unsigned* __restrict__ cnt) {
  const size_t e = (size_t)blockIdx.x * 256 + threadIdx.x;
  const int d = (*flag) ? raw[2 * ((size_t)NEDGES + e)] : raw[NEDGES + e];
  atomicAdd(&cnt[d], 1u);
}

// ---------------- prefix scan over cnt -> cursor (exclusive offsets) --------
__global__ __launch_bounds__(256) void k_scan1(const unsigned* __restrict__ cnt,
                                               unsigned* __restrict__ csum) {
  __shared__ unsigned s[256];
  const int t = threadIdx.x, b = blockIdx.x;
  s[t] = cnt[b * 512 + t] + cnt[b * 512 + 256 + t];
  __syncthreads();
  for (int off = 128; off; off >>= 1) {
    if (t < off) s[t] += s[t + off];
    __syncthreads();
  }
  if (t == 0) csum[b] = s[0];
}

__global__ void k_scan2(const unsigned* __restrict__ csum,
                        unsigned* __restrict__ coff) {
  if (threadIdx.x == 0) {
    unsigned r = 0;
    for (int i = 0; i < NCH; ++i) { coff[i] = r; r += csum[i]; }
  }
}

__global__ __launch_bounds__(256) void k_scan3(const unsigned* __restrict__ cnt,
                                               const unsigned* __restrict__ coff,
                                               unsigned* __restrict__ cursor) {
  __shared__ unsigned s[256];
  const int t = threadIdx.x, b = blockIdx.x;
  const int base = b * 512;
  const unsigned c0 = cnt[base + 2 * t], c1 = cnt[base + 2 * t + 1];
  s[t] = c0 + c1;
  __syncthreads();
  for (int off = 1; off < 256; off <<= 1) {
    unsigned v = s[t];
    if (t >= off) v += s[t - off];
    __syncthreads();
    s[t] = v;
    __syncthreads();
  }
  const unsigned o = coff[b] + s[t] - (c0 + c1);  // exclusive pair prefix
  cursor[base + 2 * t] = o;
  cursor[base + 2 * t + 1] = o + c0;
}

__global__ __launch_bounds__(256) void k_scatter(const int* __restrict__ raw,
                                                 const int* __restrict__ flag,
                                                 unsigned* __restrict__ cursor,
                                                 int2* __restrict__ sedge) {
  const size_t e = (size_t)blockIdx.x * 256 + threadIdx.x;
  int s, d;
  if (*flag) { s = raw[2 * e]; d = raw[2 * ((size_t)NEDGES + e)]; }
  else       { s = raw[e];     d = raw[NEDGES + e]; }
  const unsigned p = atomicAdd(&cursor[d], 1u);  // cursor ends at segment END
  int2 sd; sd.x = s; sd.y = d;
  sedge[p] = sd;
}

// ---------------- all weight prep in ONE kernel -----------------------------
__device__ inline void prepw_body(const float* __restrict__ W2,
                                  ushort* __restrict__ Whi,
                                  ushort* __restrict__ Wlo, int blk) {
  const int gid = blk * 256 + threadIdx.x;   // 0..2047
  const int row = gid & 15;
  const int kg  = (gid >> 4) & 3;
  const int ks  = (gid >> 6) & 3;
  const int ct  = gid >> 8;
  const int col = ct * 16 + row;
  const int k0  = ks * 32 + kg * 8;
  short8 hv, lv;
  #pragma unroll
  for (int j = 0; j < 8; ++j) {
    ushort h, l;
    bf16_split(W2[(size_t)(k0 + j) * HDIM + col], h, l);
    hv[j] = (short)h; lv[j] = (short)l;
  }
  *(short8*)(Whi + (size_t)gid * 8) = hv;
  *(short8*)(Wlo + (size_t)gid * 8) = lv;
}

__device__ inline void packab_body(const float* __restrict__ W1,
                                   ushort* __restrict__ Whi,
                                   ushort* __restrict__ Wlo, int blk) {
  const int gid = blk * 256 + threadIdx.x;   // 0..4095
  const int row = gid & 15;
  const int kg  = (gid >> 4) & 3;
  const int ks  = (gid >> 6) & 3;
  const int ct  = gid >> 8;                   // 0..15
  const int col = ct * 16 + row;
  const int k0  = ks * 32 + kg * 8;
  short8 hv, lv;
  #pragma unroll
  for (int j = 0; j < 8; ++j) {
    const int k = k0 + j;
    float v;
    if (col < HDIM) v = W1[(size_t)k * HDIM + col] - W1[(size_t)(k + HDIM) * HDIM + col];
    else            v = W1[(size_t)(k + HDIM) * HDIM + (col - HDIM)];
    ushort h, l;
    bf16_split(v, h, l);
    hv[j] = (short)h; lv[j] = (short)l;
  }
  *(short8*)(Whi + (size_t)gid * 8) = hv;
  *(short8*)(Wlo + (size_t)gid * 8) = lv;
}

__global__ __launch_bounds__(256) void k_prep_all(
    const float* __restrict__ W02, const float* __restrict__ W12,
    const float* __restrict__ W11, const float* __restrict__ W21,
    const float* __restrict__ W22, const float* __restrict__ Wf,
    const float* __restrict__ b22, const float* __restrict__ bf,
    ushort* __restrict__ W02h, ushort* __restrict__ W02l,
    ushort* __restrict__ W12h, ushort* __restrict__ W12l,
    ushort* __restrict__ W11h, ushort* __restrict__ W11l,
    ushort* __restrict__ W21h, ushort* __restrict__ W21l,
    float* __restrict__ Wfold, float* __restrict__ bfold) {
  const int b = blockIdx.x;
  if (b < 8)       prepw_body(W02, W02h, W02l, b);
  else if (b < 16) prepw_body(W12, W12h, W12l, b - 8);
  else if (b < 32) packab_body(W11, W11h, W11l, b - 16);
  else if (b < 48) packab_body(W21, W21h, W21l, b - 32);
  else {
    const int t = (b - 48) * 256 + threadIdx.x;  // 0..511
    const int f = t >> 2, o = t & 3;
    float acc = 0.f;
    for (int h = 0; h < HDIM; ++h)
      acc = fmaf(W22[f * HDIM + h], Wf[h * 4 + o], acc);
    Wfold[t] = acc;
    if (t < 4) {
      float a = bf[t];
      for (int h = 0; h < HDIM; ++h) a = fmaf(b22[h], Wf[h * 4 + t], a);
      bfold[t] = a;
    }
  }
}

// ---------------- layer-0 node projection (K=16), VALU ----------------------
__global__ __launch_bounds__(256) void k_node_ab16(const float* __restrict__ x,
                                                   const float* __restrict__ W1,
                                                   const float* __restrict__ b1,
                                                   ushort* __restrict__ Ab,
                                                   ushort* __restrict__ Bb) {
  __shared__ float s_x[16 * FDIM];
  const int tid = threadIdx.x;
  const int nb = blockIdx.x * 16;
  s_x[tid] = x[(size_t)nb * FDIM + tid];
  __syncthreads();
  const int h = tid & 127;
  const int half = tid >> 7;
  float accA[8], accB[8];
  #pragma unroll
  for (int j = 0; j < 8; ++j) { accA[j] = 0.f; accB[j] = 0.f; }
  #pragma unroll 4
  for (int f = 0; f < FDIM; ++f) {
    const float wt = W1[f * HDIM + h];
    const float wb = W1[(f + FDIM) * HDIM + h];
    const float wd = wt - wb;
    #pragma unroll
    for (int j = 0; j < 8; ++j) {
      const float xv = s_x[(half * 8 + j) * FDIM + f];
      accA[j] = fmaf(xv, wd, accA[j]);
      accB[j] = fmaf(xv, wb, accB[j]);
    }
  }
  const float bias = b1[h];
  #pragma unroll
  for (int j = 0; j < 8; ++j) {
    const size_t idx = (size_t)(nb + half * 8 + j) * HDIM + h;
    Ab[idx] = bf16_rne(accA[j] + bias);
    Bb[idx] = bf16_rne(accB[j]);
  }
}

// ---------------- layer-1 node A|B projection: 2-term MFMA ------------------
__global__ __launch_bounds__(256) void k_node_ab_mfma(
    const unsigned* __restrict__ X, const ushort* __restrict__ Whi,
    const ushort* __restrict__ Wlo, const float* __restrict__ b1,
    ushort* __restrict__ Ab, ushort* __restrict__ Bb) {
  __shared__ __align__(16) ushort s_t[64 * 128];
  const int tid = threadIdx.x;
  const int nb = blockIdx.x * 64;

  #pragma unroll
  for (int it = 0; it < 4; ++it) {
    const int idx = tid + it * 256;
    const int row = idx >> 4;
    const int kg8 = idx & 15;
    const int n = nb + row;
    float v[8];
    if (n < NNODES) {
      const unsigned* p = X + (size_t)n * HDIM + kg8 * 8;
      const uint4 u0 = *(const uint4*)p;
      const uint4 u1 = *(const uint4*)(p + 4);
      const unsigned uu[8] = {u0.x, u0.y, u0.z, u0.w, u1.x, u1.y, u1.z, u1.w};
      #pragma unroll
      for (int j = 0; j < 8; ++j)
        v[j] = (uu[j] & 0x80000000u) ? __uint_as_float(uu[j] ^ 0x80000000u) : 0.f;
    } else {
      #pragma unroll
      for (int j = 0; j < 8; ++j) v[j] = 0.f;
    }
    const short8 hv = cvtpk8_bf16(v);
    const int unit = row * 16 + (kg8 ^ (row & 15));
    *(short8*)(s_t + unit * 8) = hv;
  }
  __syncthreads();

  const int l15 = tid & 15;
  const int l4  = (tid >> 4) & 3;
  const int w   = tid >> 6;

  f32x4 acc[4][4];
  #pragma unroll
  for (int rt = 0; rt < 4; ++rt)
    #pragma unroll
    for (int c = 0; c < 4; ++c)
      #pragma unroll
      for (int r = 0; r < 4; ++r) acc[rt][c][r] = 0.f;

  #pragma unroll
  for (int ks = 0; ks < 4; ++ks) {
    short8 wh[4], wl[4];
    #pragma unroll
    for (int ctl = 0; ctl < 4; ++ctl) {
      const int ct_g = w * 4 + ctl;
      const size_t u = ((size_t)(((ct_g * 4 + ks) * 4 + l4) * 16 + l15)) * 8;
      wh[ctl] = *(const short8*)(Whi + u);
      wl[ctl] = *(const short8*)(Wlo + u);
    }
    #pragma unroll
    for (int rt = 0; rt < 4; ++rt) {
      const int unit = (rt * 16 + l15) * 16 + ((ks * 4 + l4) ^ l15);
      const short8 ah = *(const short8*)(s_t + unit * 8);
      #pragma unroll
      for (int ctl = 0; ctl < 4; ++ctl) {
        acc[rt][ctl] = __builtin_amdgcn_mfma_f32_16x16x32_bf16(ah, wl[ctl], acc[rt][ctl], 0, 0, 0);
        acc[rt][ctl] = __builtin_amdgcn_mfma_f32_16x16x32_bf16(ah, wh[ctl], acc[rt][ctl], 0, 0, 0);
      }
    }
  }

  #pragma unroll
  for (int ctl = 0; ctl < 4; ++ctl) {
    const int col_g = w * 64 + ctl * 16 + l15;
    if (col_g < HDIM) {
      const float bias = b1[col_g];
      #pragma unroll
      for (int rt = 0; rt < 4; ++rt)
        #pragma unroll
        for (int r = 0; r < 4; ++r) {
          const int n = nb + rt * 16 + l4 * 4 + r;
          if (n < NNODES) Ab[(size_t)n * HDIM + col_g] = bf16_rne(acc[rt][ctl][r] + bias);
        }
    } else {
      const int cb = col_g - HDIM;
      #pragma unroll
      for (int rt = 0; rt < 4; ++rt)
        #pragma unroll
        for (int r = 0; r < 4; ++r) {
          const int n = nb + rt * 16 + l4 * 4 + r;
          if (n < NNODES) Bb[(size_t)n * HDIM + cb] = bf16_rne(acc[rt][ctl][r]);
        }
    }
  }
}

// ---------------- layer-1 mean: wave-per-node, bf16 in/out ------------------
// Sb[n] = bf16( mean_e relu(A1[n]+B1[src]) )
__global__ __launch_bounds__(256) void k_seg_mean(const ushort* __restrict__ A,
                                                  const ushort* __restrict__ B,
                                                  const int2* __restrict__ sedge,
                                                  const unsigned* __restrict__ endv,
                                                  const unsigned* __restrict__ cnt,
                                                  ushort* __restrict__ Sb) {
  const int tid = threadIdx.x;
  const int n = blockIdx.x * 4 + (tid >> 6);
  const int lane = tid & 63;
  const unsigned deg = cnt[n];
  const unsigned end = endv[n];
  const unsigned start = end - deg;
  const unsigned a_dw = *(const unsigned*)(A + (size_t)n * HDIM + lane * 2);
  const float ax = __uint_as_float(a_dw << 16);
  const float ay = __uint_as_float(a_dw & 0xffff0000u);
  float sx = 0.f, sy = 0.f;
  for (unsigned cb = start; cb < end; cb += 64) {
    const int m = (int)((end - cb < 64u) ? (end - cb) : 64u);
    int myidx = 0;
    if (lane < m) myidx = sedge[cb + lane].x;   // 1 coalesced load per 64 edges
    int k = 0;
    for (; k + 8 <= m; k += 8) {
      unsigned bv[8];
      #pragma unroll
      for (int j = 0; j < 8; ++j) {
        const int id = __shfl(myidx, k + j);
        bv[j] = *(const unsigned*)(B + (size_t)id * HDIM + lane * 2);
      }
      #pragma unroll
      for (int j = 0; j < 8; ++j) {
        sx += fmaxf(ax + __uint_as_float(bv[j] << 16), 0.f);
        sy += fmaxf(ay + __uint_as_float(bv[j] & 0xffff0000u), 0.f);
      }
    }
    for (; k < m; ++k) {
      const int id = __shfl(myidx, k);
      const unsigned bv = *(const unsigned*)(B + (size_t)id * HDIM + lane * 2);
      sx += fmaxf(ax + __uint_as_float(bv << 16), 0.f);
      sy += fmaxf(ay + __uint_as_float(bv & 0xffff0000u), 0.f);
    }
  }
  const float sc = deg ? 1.f / (float)deg : 0.f;
  *(unsigned*)(Sb + (size_t)n * HDIM + lane * 2) = cvtpk_bf16(sx * sc, sy * sc);
}

// ---------------- fused layer-2 node pipeline (2-term, bf16 mean input) -----
__global__ __launch_bounds__(256) void k_node_l2_fused(
    const ushort* __restrict__ Sb, const unsigned* __restrict__ cnt,
    const ushort* __restrict__ W12h, const ushort* __restrict__ W12l,
    const float* __restrict__ b12,
    const ushort* __restrict__ W21h, const ushort* __restrict__ W21l,
    const float* __restrict__ b21,
    ushort* __restrict__ A2, ushort* __restrict__ B2) {
  __shared__ __align__(16) ushort s_t[64 * 128];
  __shared__ float s_m[64 * 132];
  __shared__ float s_alive[64];
  const int tid = threadIdx.x;
  const int nb = blockIdx.x * 64;
  if (tid < 64) {
    const int n = nb + tid;
    const unsigned c = (n < NNODES) ? cnt[n] : 0u;
    s_alive[tid] = c ? 1.f : 0.f;
  }

  // stage bf16 mean -> LDS (pure 16B copy, swizzled)
  #pragma unroll
  for (int it = 0; it < 4; ++it) {
    const int idx = tid + it * 256;
    const int row = idx >> 4;
    const int kg8 = idx & 15;
    const int n = nb + row;
    short8 hv;
    if (n < NNODES) hv = *(const short8*)(Sb + (size_t)n * HDIM + kg8 * 8);
    else {
      #pragma unroll
      for (int j = 0; j < 8; ++j) hv[j] = 0;
    }
    const int unit = row * 16 + (kg8 ^ (row & 15));
    *(short8*)(s_t + unit * 8) = hv;
  }
  __syncthreads();

  const int l15 = tid & 15;
  const int l4  = (tid >> 4) & 3;
  const int w   = tid >> 6;

  // ---- GEMM1: 128 cols (2 ctl/wave), 2-term ----
  {
    f32x4 acc[4][2];
    #pragma unroll
    for (int rt = 0; rt < 4; ++rt)
      #pragma unroll
      for (int c = 0; c < 2; ++c)
        #pragma unroll
        for (int r = 0; r < 4; ++r) acc[rt][c][r] = 0.f;

    #pragma unroll
    for (int ks = 0; ks < 4; ++ks) {
      short8 wh[2], wl[2];
      #pragma unroll
      for (int ctl = 0; ctl < 2; ++ctl) {
        const int ct_g = w * 2 + ctl;
        const size_t u = ((size_t)(((ct_g * 4 + ks) * 4 + l4) * 16 + l15)) * 8;
        wh[ctl] = *(const short8*)(W12h + u);
        wl[ctl] = *(const short8*)(W12l + u);
      }
      #pragma unroll
      for (int rt = 0; rt < 4; ++rt) {
        const int unit = (rt * 16 + l15) * 16 + ((ks * 4 + l4) ^ l15);
        const short8 ah = *(const short8*)(s_t + unit * 8);
        #pragma unroll
        for (int ctl = 0; ctl < 2; ++ctl) {
          acc[rt][ctl] = __builtin_amdgcn_mfma_f32_16x16x32_bf16(ah, wl[ctl], acc[rt][ctl], 0, 0, 0);
          acc[rt][ctl] = __builtin_amdgcn_mfma_f32_16x16x32_bf16(ah, wh[ctl], acc[rt][ctl], 0, 0, 0);
        }
      }
    }

    const float bb0 = b12[w * 32 + l15];
    const float bb1 = b12[w * 32 + 16 + l15];
    #pragma unroll
    for (int rt = 0; rt < 4; ++rt)
      #pragma unroll
      for (int ctl = 0; ctl < 2; ++ctl)
        #pragma unroll
        for (int r = 0; r < 4; ++r) {
          const int row = rt * 16 + l4 * 4 + r;
          s_m[row * 132 + w * 32 + ctl * 16 + l15] =
              fmaxf(acc[rt][ctl][r] + (ctl ? bb1 : bb0), 0.f) * s_alive[row];
        }
  }
  __syncthreads();

  // restage h2 -> bf16 staging LDS
  #pragma unroll
  for (int it = 0; it < 4; ++it) {
    const int idx = tid + it * 256;
    const int row = idx >> 4;
    const int kg8 = idx & 15;
    const float* p = s_m + row * 132 + kg8 * 8;
    float v[8];
    const float4 a0 = *(const float4*)p;
    const float4 a1 = *(const float4*)(p + 4);
    v[0] = a0.x; v[1] = a0.y; v[2] = a0.z; v[3] = a0.w;
    v[4] = a1.x; v[5] = a1.y; v[6] = a1.z; v[7] = a1.w;
    const short8 hv = cvtpk8_bf16(v);
    const int unit = row * 16 + (kg8 ^ (row & 15));
    *(short8*)(s_t + unit * 8) = hv;
  }
  __syncthreads();

  // ---- GEMM2: 256 cols (4 ctl/wave), 2-term ----
  f32x4 acc2[4][4];
  #pragma unroll
  for (int rt = 0; rt < 4; ++rt)
    #pragma unroll
    for (int c = 0; c < 4; ++c)
      #pragma unroll
      for (int r = 0; r < 4; ++r) acc2[rt][c][r] = 0.f;

  #pragma unroll
  for (int ks = 0; ks < 4; ++ks) {
    short8 wh[4], wl[4];
    #pragma unroll
    for (int ctl = 0; ctl < 4; ++ctl) {
      const int ct_g = w * 4 + ctl;
      const size_t u = ((size_t)(((ct_g * 4 + ks) * 4 + l4) * 16 + l15)) * 8;
      wh[ctl] = *(const short8*)(W21h + u);
      wl[ctl] = *(const short8*)(W21l + u);
    }
    #pragma unroll
    for (int rt = 0; rt < 4; ++rt) {
      const int unit = (rt * 16 + l15) * 16 + ((ks * 4 + l4) ^ l15);
      const short8 ah = *(const short8*)(s_t + unit * 8);
      #pragma unroll
      for (int ctl = 0; ctl < 4; ++ctl) {
        acc2[rt][ctl] = __builtin_amdgcn_mfma_f32_16x16x32_bf16(ah, wl[ctl], acc2[rt][ctl], 0, 0, 0);
        acc2[rt][ctl] = __builtin_amdgcn_mfma_f32_16x16x32_bf16(ah, wh[ctl], acc2[rt][ctl], 0, 0, 0);
      }
    }
  }

  #pragma unroll
  for (int ctl = 0; ctl < 4; ++ctl) {
    const int col_g = w * 64 + ctl * 16 + l15;
    if (col_g < HDIM) {
      const float bias = b21[col_g];
      #pragma unroll
      for (int rt = 0; rt < 4; ++rt)
        #pragma unroll
        for (int r = 0; r < 4; ++r) {
          const int n = nb + rt * 16 + l4 * 4 + r;
          if (n < NNODES) A2[(size_t)n * HDIM + col_g] = bf16_rne(acc2[rt][ctl][r] + bias);
        }
    } else {
      const int cb = col_g - HDIM;
      #pragma unroll
      for (int rt = 0; rt < 4; ++rt)
        #pragma unroll
        for (int r = 0; r < 4; ++r) {
          const int n = nb + rt * 16 + l4 * 4 + r;
          if (n < NNODES) B2[(size_t)n * HDIM + cb] = bf16_rne(acc2[rt][ctl][r]);
        }
    }
  }
}

// ---------------- layer 0: single-bf16 MFMA edge GEMM + register seg-max ----
__global__ __launch_bounds__(256) void k_edge_l0_mfma(
    const ushort* __restrict__ A0b, const ushort* __restrict__ B0b,
    const int2* __restrict__ sedge,
    const ushort* __restrict__ Whi,
    const float* __restrict__ b2, unsigned* __restrict__ outenc) {
  __shared__ __align__(16) char s_un[4 * 64 * 17 * 4];  // m slabs 17408B | t 16384B
  __shared__ int s_dstA[64];
  __shared__ int s_srcA[64];
  ushort* s_t = (ushort*)s_un;
  float*  s_m = (float*)s_un;

  const int tid = threadIdx.x;
  const int eb = blockIdx.x * 64;
  if (tid < 64) {
    const int2 sd = sedge[eb + tid];
    s_srcA[tid] = sd.x;
    s_dstA[tid] = sd.y;
  }
  __syncthreads();

  #pragma unroll
  for (int it = 0; it < 4; ++it) {
    const int idx = tid + it * 256;
    const int e = idx >> 4;
    const int kg8 = idx & 15;
    const int k0 = kg8 * 8;
    const short8 a8 = *(const short8*)(A0b + (size_t)s_dstA[e] * HDIM + k0);
    const short8 b8 = *(const short8*)(B0b + (size_t)s_srcA[e] * HDIM + k0);
    float v[8];
    #pragma unroll
    for (int j = 0; j < 8; ++j) {
      const float av = __uint_as_float(((unsigned)(ushort)a8[j]) << 16);
      const float bv = __uint_as_float(((unsigned)(ushort)b8[j]) << 16);
      v[j] = fmaxf(av + bv, 0.f);
    }
    const short8 hv = cvtpk8_bf16(v);
    const int unit = e * 16 + (kg8 ^ (e & 15));
    *(short8*)(s_t + unit * 8) = hv;
  }
  __syncthreads();

  const int l15 = tid & 15;
  const int l4  = (tid >> 4) & 3;
  const int w   = tid >> 6;

  f32x4 acc[4][2];
  #pragma unroll
  for (int rt = 0; rt < 4; ++rt)
    #pragma unroll
    for (int c = 0; c < 2; ++c)
      #pragma unroll
      for (int r = 0; r < 4; ++r) acc[rt][c][r] = 0.f;

  #pragma unroll
  for (int ks = 0; ks < 4; ++ks) {
    short8 wh[2];
    #pragma unroll
    for (int ctl = 0; ctl < 2; ++ctl) {
      const int ct_g = w * 2 + ctl;
      const size_t u = ((size_t)(((ct_g * 4 + ks) * 4 + l4) * 16 + l15)) * 8;
      wh[ctl] = *(const short8*)(Whi + u);
    }
    #pragma unroll
    for (int rt = 0; rt < 4; ++rt) {
      const int e = rt * 16 + l15;
      const int unit = e * 16 + ((ks * 4 + l4) ^ l15);
      const short8 ah = *(const short8*)(s_t + unit * 8);
      #pragma unroll
      for (int ctl = 0; ctl < 2; ++ctl)
        acc[rt][ctl] = __builtin_amdgcn_mfma_f32_16x16x32_bf16(ah, wh[ctl], acc[rt][ctl], 0, 0, 0);
    }
  }
  __syncthreads();

  // 2-pass epilogue with register-prefetched segmented max
  float* smw = s_m + w * (64 * 17);
  const int le = tid & 63;
  const int colw = le & 15;
  const int g = le >> 4;
  const int e0 = g * 16;
  int dd[16];
  #pragma unroll
  for (int e = 0; e < 16; ++e) dd[e] = s_dstA[e0 + e];
  #pragma unroll
  for (int ctl = 0; ctl < 2; ++ctl) {
    const float bb = b2[w * 32 + ctl * 16 + l15];
    #pragma unroll
    for (int rt = 0; rt < 4; ++rt)
      #pragma unroll
      for (int r = 0; r < 4; ++r)
        smw[(rt * 16 + l4 * 4 + r) * 17 + l15] = acc[rt][ctl][r] + bb;
    float vv[16];
    #pragma unroll
    for (int e = 0; e < 16; ++e) vv[e] = smw[(e0 + e) * 17 + colw];
    unsigned* const ocol = outenc + w * 32 + ctl * 16 + colw;
    int curd = dd[0];
    float run = vv[0];
    #pragma unroll
    for (int e = 1; e < 16; ++e) {
      const bool same = (dd[e] == curd);
      if (!same) atomicMax(ocol + (size_t)curd * HDIM, enc_f32(run));
      run = same ? fmaxf(run, vv[e]) : vv[e];
      curd = dd[e];
    }
    atomicMax(ocol + (size_t)curd * HDIM, enc_f32(run));
  }
}

// ---------------- layer-2 mean fused with final fc (A2/B2 bf16) -------------
__global__ __launch_bounds__(256) void k_seg_final(const ushort* __restrict__ A,
                                                   const ushort* __restrict__ B,
                                                   const int2* __restrict__ sedge,
                                                   const unsigned* __restrict__ endv,
                                                   const unsigned* __restrict__ cnt,
                                                   const float* __restrict__ Wfold,
                                                   const float* __restrict__ bfold,
                                                   const float* __restrict__ bf,
                                                   float* __restrict__ out) {
  const int tid = threadIdx.x;
  const int n = blockIdx.x * 4 + (tid >> 6);
  const int lane = tid & 63;
  const unsigned deg = cnt[n];
  if (deg == 0) {
    if (lane == 0) {
      float4 o; o.x = bf[0]; o.y = bf[1]; o.z = bf[2]; o.w = bf[3];
      ((float4*)out)[n] = o;
    }
    return;
  }
  const unsigned end = endv[n];
  const unsigned start = end - deg;
  const unsigned a_dw = *(const unsigned*)(A + (size_t)n * HDIM + lane * 2);
  const float ax = __uint_as_float(a_dw << 16);
  const float ay = __uint_as_float(a_dw & 0xffff0000u);
  float sx = 0.f, sy = 0.f;
  for (unsigned cb = start; cb < end; cb += 64) {
    const int m = (int)((end - cb < 64u) ? (end - cb) : 64u);
    int myidx = 0;
    if (lane < m) myidx = sedge[cb + lane].x;
    int k = 0;
    for (; k + 8 <= m; k += 8) {
      unsigned bv[8];
      #pragma unroll
      for (int j = 0; j < 8; ++j) {
        const int id = __shfl(myidx, k + j);
        bv[j] = *(const unsigned*)(B + (size_t)id * HDIM + lane * 2);
      }
      #pragma unroll
      for (int j = 0; j < 8; ++j) {
        sx += fmaxf(ax + __uint_as_float(bv[j] << 16), 0.f);
        sy += fmaxf(ay + __uint_as_float(bv[j] & 0xffff0000u), 0.f);
      }
    }
    for (; k < m; ++k) {
      const int id = __shfl(myidx, k);
      const unsigned bv = *(const unsigned*)(B + (size_t)id * HDIM + lane * 2);
      sx += fmaxf(ax + __uint_as_float(bv << 16), 0.f);
      sy += fmaxf(ay + __uint_as_float(bv & 0xffff0000u), 0.f);
    }
  }
  const float inv = 1.f / (float)deg;
  const float vx = sx * inv, vy = sy * inv;
  const float4 w0 = ((const float4*)Wfold)[lane * 2];
  const float4 w1 = ((const float4*)Wfold)[lane * 2 + 1];
  float p0 = fmaf(vx, w0.x, vy * w1.x);
  float p1 = fmaf(vx, w0.y, vy * w1.y);
  float p2 = fmaf(vx, w0.z, vy * w1.z);
  float p3 = fmaf(vx, w0.w, vy * w1.w);
  #pragma unroll
  for (int off = 32; off; off >>= 1) {
    p0 += __shfl_xor(p0, off);
    p1 += __shfl_xor(p1, off);
    p2 += __shfl_xor(p2, off);
    p3 += __shfl_xor(p3, off);
  }
  if (lane == 0) {
    float4 o;
    o.x = p0 + bfold[0]; o.y = p1 + bfold[1];
    o.z = p2 + bfold[2]; o.w = p3 + bfold[3];
    ((float4*)out)[n] = o;
  }
}

// ----------------------------------------------------------------------------
extern "C" void kernel_launch(void* const* d_in, const int* in_sizes, int n_in,
                              void* d_out, int out_size, void* d_ws, size_t ws_size,
                              hipStream_t stream) {
  const float* x   = (const float*)d_in[0];
  // d_in[1] = edge_attr: unused in math
  const int*   eidx = (const int*)d_in[2];
  const float* W01 = (const float*)d_in[3];
  const float* b01 = (const float*)d_in[4];
  const float* W02 = (const float*)d_in[5];
  const float* b02 = (const float*)d_in[6];
  const float* W11 = (const float*)d_in[7];
  const float* b11 = (const float*)d_in[8];
  const float* W12 = (const float*)d_in[9];
  const float* b12 = (const float*)d_in[10];
  const float* W21 = (const float*)d_in[11];
  const float* b21 = (const float*)d_in[12];
  const float* W22 = (const float*)d_in[13];
  const float* b22 = (const float*)d_in[14];
  const float* Wf  = (const float*)d_in[15];
  const float* bf  = (const float*)d_in[16];
  float* out = (float*)d_out;
  char* ws = (char*)d_ws;

  unsigned* enc = (unsigned*)(ws + OFF_ENC);
  ushort* Sb = (ushort*)(ws + OFF_ENC);  // bf16 mean, overlays enc (enc consumed first)
  ushort* PA = (ushort*)(ws + OFF_PA);   // A0 then A2
  ushort* PB = (ushort*)(ws + OFF_PB);   // B0 then B2
  ushort* QA = (ushort*)(ws + OFF_QA);   // A1
  ushort* QB = (ushort*)(ws + OFF_QB);   // B1
  unsigned* cnt    = (unsigned*)(ws + OFF_CNT);
  unsigned* cursor = (unsigned*)(ws + OFF_CUR);
  unsigned* csum   = (unsigned*)(ws + OFF_CSUM);
  unsigned* coff   = (unsigned*)(ws + OFF_COFF);
  float* Wfold = (float*)(ws + OFF_WFOLD);
  float* bfold = (float*)(ws + OFF_BFOLD);
  int* flag  = (int*)(ws + OFF_FLAG);
  int2* sedge = (int2*)(ws + OFF_SEDGE);
  ushort* W02h = (ushort*)(ws + OFF_W02H);
  ushort* W02l = (ushort*)(ws + OFF_W02L);
  ushort* W12h = (ushort*)(ws + OFF_W12H);
  ushort* W12l = (ushort*)(ws + OFF_W12L);
  ushort* W11h = (ushort*)(ws + OFF_W11H);
  ushort* W11l = (ushort*)(ws + OFF_W11L);
  ushort* W21h = (ushort*)(ws + OFF_W21H);
  ushort* W21l = (ushort*)(ws + OFF_W21L);

  // ---- init (zero enc+cnt, detect dtype) + counting sort + weight prep ----
  k_init<<<(int)(NH / 256), 256, 0, stream>>>(eidx, flag, cnt, enc);
  k_count<<<NEDGES / 256, 256, 0, stream>>>(eidx, flag, cnt);
  k_scan1<<<NCH, 256, 0, stream>>>(cnt, csum);
  k_scan2<<<1, 64, 0, stream>>>(csum, coff);
  k_scan3<<<NCH, 256, 0, stream>>>(cnt, coff, cursor);
  k_scatter<<<NEDGES / 256, 256, 0, stream>>>(eidx, flag, cursor, sedge);
  // after scatter: cursor[n] == segment end offset of node n
  k_prep_all<<<50, 256, 0, stream>>>(W02, W12, W11, W21, W22, Wf, b22, bf,
                                     W02h, W02l, W12h, W12l, W11h, W11l,
                                     W21h, W21l, Wfold, bfold);

  // ---- layer 0 (max aggr) ----
  k_node_ab16<<<NNODES / 16, 256, 0, stream>>>(x, W01, b01, PA, PB);
  k_edge_l0_mfma<<<NEDGES / 64, 256, 0, stream>>>(PA, PB, sedge, W02h, b02, enc);

  // ---- layer 1: projections (2-term), then wave-per-node mean -> bf16 ----
  k_node_ab_mfma<<<NBLK64, 256, 0, stream>>>(enc, W11h, W11l, b11, QA, QB);
  k_seg_mean<<<NNODES / 4, 256, 0, stream>>>(QA, QB, sedge, cursor, cnt, Sb);

  // ---- layer 2: GEMM1+GEMM2 fused (2-term), then mean+final fused ----
  k_node_l2_fused<<<NBLK64, 256, 0, stream>>>(Sb, cnt, W12h, W12l, b12,
                                              W21h, W21l, b21, PA, PB);
  k_seg_final<<<NNODES / 4, 256, 0, stream>>>(PA, PB, sedge, cursor, cnt,
                                              Wfold, bfold, bf, out);

  (void)in_sizes; (void)n_in; (void)out_size; (void)ws_size;
}